// Round 4
// baseline (187.961 us; speedup 1.0000x reference)
//
#include <hip/hip_runtime.h>
#include <hip/hip_bf16.h>

// ContrastiveLoss: ys [4096,2048] f32, labels [4096] i32 -> scalar f32
// loss = mean over strict lower triangle of: same ? relu(2-cos)^2 : cos^2
// cos = pairwise cosine similarity of rows of ys (norm clamped at 1e-6).
//
// Round-4 structure: NO LDS staging in the GEMM. yn (16 MB bf16) is
// L3-resident; MFMA fragments are loaded directly from global memory with
// full coalescing (wave load = 16 rows x 64 contiguous bytes). 128x128
// tiles, 4 waves of 64x64 (4x4 fragments), zero barriers in the K-loop.

#define ROWS 4096
#define KDIM 2048
// 128x128 tiles over lower triangle incl. diagonal: 32*33/2 = 528 jobs.
#define NJOBS 528

typedef __bf16 bf16x8 __attribute__((ext_vector_type(8)));
typedef float f32x4 __attribute__((ext_vector_type(4)));

__device__ __forceinline__ unsigned short f2bf(float f) {
    unsigned u = __float_as_uint(f);
    unsigned r = (u + 0x7FFFu + ((u >> 16) & 1u)) >> 16;  // RNE
    return (unsigned short)r;
}

// ---------------- Kernel 1: row normalize, f32 -> bf16 --------------------
__global__ __launch_bounds__(256) void normalize_rows(
    const float* __restrict__ ys, unsigned short* __restrict__ yn) {
    int row = blockIdx.x;
    const float4* src = (const float4*)(ys + (size_t)row * KDIM);
    float4 vals[2];
    float ss = 0.f;
#pragma unroll
    for (int i = 0; i < 2; ++i) {
        float4 v = src[threadIdx.x + i * 256];
        vals[i] = v;
        ss += v.x * v.x + v.y * v.y + v.z * v.z + v.w * v.w;
    }
#pragma unroll
    for (int off = 32; off > 0; off >>= 1) ss += __shfl_down(ss, off);
    __shared__ float red[4];
    int lane = threadIdx.x & 63, wv = threadIdx.x >> 6;
    if (lane == 0) red[wv] = ss;
    __syncthreads();
    float tot = red[0] + red[1] + red[2] + red[3];
    float inv = 1.0f / fmaxf(sqrtf(tot), 1e-6f);
    ushort4* dst = (ushort4*)(yn + (size_t)row * KDIM);
#pragma unroll
    for (int i = 0; i < 2; ++i) {
        float4 v = vals[i];
        ushort4 o;
        o.x = f2bf(v.x * inv);
        o.y = f2bf(v.y * inv);
        o.z = f2bf(v.z * inv);
        o.w = f2bf(v.w * inv);
        dst[threadIdx.x + i * 256] = o;
    }
}

// ---------------- Kernel 2: direct-global 128x128 Gram + loss -------------
// 528 linear blocks -> (bi,bj) lower-triangle tile jobs. 4 waves in 2x2;
// each wave owns a 64x64 subtile (4x4 frags of 16x16). Fragments load
// straight from global (L1/L2/L3-resident); no LDS, no K-loop barriers.
__global__ __launch_bounds__(256) void gram_loss(
    const unsigned short* __restrict__ yn, const int* __restrict__ labels,
    float* __restrict__ partials) {
    // XCD-chunk swizzle (bijective: 528 % 8 == 0, 66 jobs per XCD):
    int t = (blockIdx.x & 7) * (NJOBS / 8) + (blockIdx.x >> 3);
    // job t -> (bi, bj): jobs for bi occupy [bi(bi+1)/2, (bi+1)(bi+2)/2)
    int bi = (int)((sqrtf(8.0f * t + 1.0f) - 1.0f) * 0.5f);
    while (bi * (bi + 1) / 2 > t) --bi;
    while ((bi + 1) * (bi + 2) / 2 <= t) ++bi;
    int bj = t - bi * (bi + 1) / 2;

    __shared__ int labI[128];
    __shared__ int labJ[128];
    __shared__ float red[4];

    int tid = threadIdx.x, lane = tid & 63, wv = tid >> 6;
    int wr = wv >> 1, wc = wv & 1;
    int rowA = bi * 128, rowB = bj * 128;

    if (tid < 128) labI[tid] = labels[rowA + tid];
    else labJ[tid - 128] = labels[rowB + tid - 128];

    int colB = lane & 15;  // spatial index within 16x16 fragment
    int kq = lane >> 4;    // k-quarter: lane holds k = k0 + 8*kq .. +7

    // Per-lane base pointers: row = tileRow + w*64 + colB (+ m*16 via offset),
    // k-offset = kq*8 shorts. Each wave-load touches 16 rows x 64B contiguous.
    const unsigned short* baseA = yn + (size_t)(rowA + wr * 64 + colB) * KDIM + kq * 8;
    const unsigned short* baseB = yn + (size_t)(rowB + wc * 64 + colB) * KDIM + kq * 8;

    f32x4 zero = {0.f, 0.f, 0.f, 0.f};
    f32x4 acc[4][4];
#pragma unroll
    for (int m = 0; m < 4; ++m)
#pragma unroll
        for (int n = 0; n < 4; ++n) acc[m][n] = zero;

#pragma unroll 4
    for (int k = 0; k < KDIM; k += 32) {
        bf16x8 af[4], bfr[4];
#pragma unroll
        for (int m = 0; m < 4; ++m)
            af[m] = *(const bf16x8*)(baseA + (size_t)m * 16 * KDIM + k);
#pragma unroll
        for (int n = 0; n < 4; ++n)
            bfr[n] = *(const bf16x8*)(baseB + (size_t)n * 16 * KDIM + k);
#pragma unroll
        for (int m = 0; m < 4; ++m)
#pragma unroll
            for (int n = 0; n < 4; ++n)
                acc[m][n] = __builtin_amdgcn_mfma_f32_16x16x32_bf16(
                    af[m], bfr[n], acc[m][n], 0, 0, 0);
    }

    __syncthreads();  // labels staged at start are visible

    // fused loss epilogue: ti = wr*64+m*16+kq*4+j, tj = wc*64+n*16+colB
    float lsum = 0.f;
#pragma unroll
    for (int m = 0; m < 4; ++m) {
#pragma unroll
        for (int n = 0; n < 4; ++n) {
#pragma unroll
            for (int j = 0; j < 4; ++j) {
                int ti = wr * 64 + m * 16 + kq * 4 + j;
                int tj = wc * 64 + n * 16 + colB;
                int gi = rowA + ti, gj = rowB + tj;
                if (gi > gj) {
                    float c = acc[m][n][j];
                    float v = (labI[ti] == labJ[tj]) ? fmaxf(2.0f - c, 0.0f) : c;
                    lsum += v * v;
                }
            }
        }
    }
#pragma unroll
    for (int off = 32; off > 0; off >>= 1) lsum += __shfl_down(lsum, off);
    if (lane == 0) red[wv] = lsum;
    __syncthreads();
    if (tid == 0) partials[blockIdx.x] = red[0] + red[1] + red[2] + red[3];
}

// ---------------- Kernel 3: deterministic final reduction -----------------
__global__ __launch_bounds__(256) void finalize(
    const float* __restrict__ partials, float* __restrict__ out) {
    float s = 0.f;
    for (int i = threadIdx.x; i < NJOBS; i += 256) s += partials[i];
#pragma unroll
    for (int off = 32; off > 0; off >>= 1) s += __shfl_down(s, off);
    __shared__ float red[4];
    int lane = threadIdx.x & 63, wv = threadIdx.x >> 6;
    if (lane == 0) red[wv] = s;
    __syncthreads();
    if (threadIdx.x == 0) {
        const double npair = (double)ROWS * (ROWS - 1) / 2.0;
        out[0] = (float)((double)(red[0] + red[1] + red[2] + red[3]) / npair);
    }
}

extern "C" void kernel_launch(void* const* d_in, const int* in_sizes, int n_in,
                              void* d_out, int out_size, void* d_ws, size_t ws_size,
                              hipStream_t stream) {
    const float* ys = (const float*)d_in[0];
    const int* labels = (const int*)d_in[1];
    float* out = (float*)d_out;

    unsigned short* yn = (unsigned short*)d_ws;                         // 16 MB bf16
    float* partials = (float*)((char*)d_ws + (size_t)ROWS * KDIM * 2);  // 2.1 KB

    normalize_rows<<<ROWS, 256, 0, stream>>>(ys, yn);
    gram_loss<<<NJOBS, 256, 0, stream>>>(yn, labels, partials);
    finalize<<<1, 256, 0, stream>>>(partials, out);
}

// Round 5
// 52.945 us; speedup vs baseline: 3.5501x; 3.5501x over previous
//
#include <hip/hip_runtime.h>

// ContrastiveLoss: ys [4096,2048] f32, labels [4096] i32 -> scalar f32
// loss = mean over strict lower triangle of: same ? relu(2-cos)^2 : cos^2
// cos = pairwise cosine similarity of rows of ys (norm clamped at 1e-6).
//
// Round-5: round-2 structure (128x64 tiles, single-buffer LDS, 2 barriers
// per K-step) with fp8-e4m3 staging: half the staged bytes, half the
// K-steps (BK=128 elements = same 128B/row LDS geometry), same MFMA count
// via mfma_f32_16x16x32_fp8_fp8. yn pre-scaled by 32 so typical elements
// sit in e4m3 normal range; epilogue divides by 32*32=1024.

#define ROWS 4096
#define KDIM 2048
// Tile decomposition: 128-row x 64-col tiles over the lower triangle.
// bi in [0,32), bj in [0,64); keep bj <= 2*bi+1  -> sum(2bi+2) = 1056 jobs.
#define NJOBS 1056
#define BK 128          // k-elements (= bytes) per K-step
#define FSCALE 32.0f    // fp8 pre-scale
#define FSCALE2_INV (1.0f / (FSCALE * FSCALE))

typedef float f32x4 __attribute__((ext_vector_type(4)));
typedef long long fragq;  // 8 x fp8 (2 VGPR) MFMA operand

__device__ __forceinline__ void async_copy16(const unsigned char* g, unsigned char* l) {
    __builtin_amdgcn_global_load_lds(
        (const __attribute__((address_space(1))) void*)g,
        (__attribute__((address_space(3))) void*)l,
        16, 0, 0);
}

// ---------------- Kernel 1: row normalize, f32 -> fp8 e4m3 (x32) ----------
__global__ __launch_bounds__(256) void normalize_rows(
    const float* __restrict__ ys, unsigned int* __restrict__ yn) {
    int row = blockIdx.x;
    const float4* src = (const float4*)(ys + (size_t)row * KDIM);
    float4 vals[2];
    float ss = 0.f;
#pragma unroll
    for (int i = 0; i < 2; ++i) {
        float4 v = src[threadIdx.x + i * 256];
        vals[i] = v;
        ss += v.x * v.x + v.y * v.y + v.z * v.z + v.w * v.w;
    }
#pragma unroll
    for (int off = 32; off > 0; off >>= 1) ss += __shfl_down(ss, off);
    __shared__ float red[4];
    int lane = threadIdx.x & 63, wv = threadIdx.x >> 6;
    if (lane == 0) red[wv] = ss;
    __syncthreads();
    float tot = red[0] + red[1] + red[2] + red[3];
    float inv = FSCALE / fmaxf(sqrtf(tot), 1e-6f);
    unsigned int* dst = yn + (size_t)row * (KDIM / 4);
#pragma unroll
    for (int i = 0; i < 2; ++i) {
        float4 v = vals[i];
        int p = __builtin_amdgcn_cvt_pk_fp8_f32(v.x * inv, v.y * inv, 0, false);
        p = __builtin_amdgcn_cvt_pk_fp8_f32(v.z * inv, v.w * inv, p, true);
        dst[threadIdx.x + i * 256] = (unsigned int)p;
    }
}

// ---------------- Kernel 2: 128x64 Gram tile + fused loss -----------------
// 1056 linear blocks -> (bi,bj) lower-triangle jobs. 4 waves in 2x2; each
// wave owns a 64x32 subtile. Single-buffer LDS, 2 barriers per K-step
// (round-2 proven structure), fp8 elements.
__global__ __launch_bounds__(256) void gram_loss(
    const unsigned char* __restrict__ yn, const int* __restrict__ labels,
    float* __restrict__ partials) {
    // XCD-chunk swizzle (bijective: 1056 % 8 == 0, 132 jobs per XCD):
    int t = (blockIdx.x & 7) * (NJOBS / 8) + (blockIdx.x >> 3);
    // job t -> (bi, bj): jobs for bi occupy [bi*(bi+1), bi*(bi+1)+2bi+2)
    int bi = (int)((sqrtf((float)(4 * t + 1)) - 1.0f) * 0.5f);
    while (bi * (bi + 1) > t) --bi;
    while ((bi + 1) * (bi + 2) <= t) ++bi;
    int bj = t - bi * (bi + 1);

    __shared__ __attribute__((aligned(16))) unsigned char As[128 * BK];  // 16KB
    __shared__ __attribute__((aligned(16))) unsigned char Bs[64 * BK];   // 8KB
    __shared__ int labI[128];
    __shared__ int labJ[64];
    __shared__ float red[4];

    int tid = threadIdx.x, lane = tid & 63, wv = tid >> 6;
    int wr = wv >> 1, wc = wv & 1;
    int rowA = bi * 128, rowB = bj * 64;

    if (tid < 128) labI[tid] = labels[rowA + tid];
    else if (tid < 192) labJ[tid - 128] = labels[rowB + tid - 128];

    // staging: chunk = 8 rows x 128 fp8 (1KB). lane covers row lane>>3,
    // 16B granule (lane&7) pre-XORed with row so linear LDS writes land
    // swizzled: byte ^= ((row&7)<<4).
    int srow = lane >> 3;
    int sbyte = ((lane & 7) ^ srow) * 16;

    f32x4 zero = {0.f, 0.f, 0.f, 0.f};
    f32x4 acc[4][2];
#pragma unroll
    for (int m = 0; m < 4; ++m)
#pragma unroll
        for (int n = 0; n < 2; ++n) acc[m][n] = zero;

    int colB = lane & 15;  // spatial index within 16x16 fragment
    int kq = lane >> 4;    // k-quarter: lane holds k = kk + 8*kq .. +7

    for (int k0 = 0; k0 < KDIM; k0 += BK) {
        __syncthreads();  // previous tile fully consumed (labels on 1st iter)
        // 24 chunks: 0..15 -> A (16KB), 16..23 -> B (8KB); 6 iters x 4 waves
#pragma unroll
        for (int it = 0; it < 6; ++it) {
            int chunk = it * 4 + wv;
            if (chunk < 16) {
                int rr = chunk * 8 + srow;
                async_copy16(yn + (size_t)(rowA + rr) * KDIM + k0 + sbyte,
                             As + chunk * 1024);
            } else {
                int c2 = chunk - 16;
                int rr = c2 * 8 + srow;
                async_copy16(yn + (size_t)(rowB + rr) * KDIM + k0 + sbyte,
                             Bs + c2 * 1024);
            }
        }
        __syncthreads();  // vmcnt(0) drained by syncthreads semantics

#pragma unroll
        for (int kk = 0; kk < BK; kk += 32) {
            int kidx = kk + 8 * kq;
            fragq af[4], bfr[2];
#pragma unroll
            for (int m = 0; m < 4; ++m) {
                int row = wr * 64 + m * 16 + colB;
                int byte = (row * BK + kidx) ^ ((row & 7) << 4);
                af[m] = *(const fragq*)(As + byte);
            }
#pragma unroll
            for (int n = 0; n < 2; ++n) {
                int row = wc * 32 + n * 16 + colB;
                int byte = (row * BK + kidx) ^ ((row & 7) << 4);
                bfr[n] = *(const fragq*)(Bs + byte);
            }
#pragma unroll
            for (int m = 0; m < 4; ++m)
#pragma unroll
                for (int n = 0; n < 2; ++n)
                    acc[m][n] = __builtin_amdgcn_mfma_f32_16x16x32_fp8_fp8(
                        af[m], bfr[n], acc[m][n], 0, 0, 0);
        }
    }

    // fused loss epilogue: ti = wr*64+m*16+kq*4+j, tj = wc*32+n*16+colB
    float lsum = 0.f;
#pragma unroll
    for (int m = 0; m < 4; ++m) {
#pragma unroll
        for (int n = 0; n < 2; ++n) {
#pragma unroll
            for (int j = 0; j < 4; ++j) {
                int ti = wr * 64 + m * 16 + kq * 4 + j;
                int tj = wc * 32 + n * 16 + colB;
                int gi = rowA + ti, gj = rowB + tj;
                if (gi > gj) {
                    float c = acc[m][n][j] * FSCALE2_INV;
                    float v = (labI[ti] == labJ[tj]) ? fmaxf(2.0f - c, 0.0f) : c;
                    lsum += v * v;
                }
            }
        }
    }
#pragma unroll
    for (int off = 32; off > 0; off >>= 1) lsum += __shfl_down(lsum, off);
    if (lane == 0) red[wv] = lsum;
    __syncthreads();
    if (tid == 0) partials[blockIdx.x] = red[0] + red[1] + red[2] + red[3];
}

// ---------------- Kernel 3: deterministic final reduction -----------------
__global__ __launch_bounds__(256) void finalize(
    const float* __restrict__ partials, float* __restrict__ out) {
    float s = 0.f;
    for (int i = threadIdx.x; i < NJOBS; i += 256) s += partials[i];
#pragma unroll
    for (int off = 32; off > 0; off >>= 1) s += __shfl_down(s, off);
    __shared__ float red[4];
    int lane = threadIdx.x & 63, wv = threadIdx.x >> 6;
    if (lane == 0) red[wv] = s;
    __syncthreads();
    if (threadIdx.x == 0) {
        const double npair = (double)ROWS * (ROWS - 1) / 2.0;
        out[0] = (float)((double)(red[0] + red[1] + red[2] + red[3]) / npair);
    }
}

extern "C" void kernel_launch(void* const* d_in, const int* in_sizes, int n_in,
                              void* d_out, int out_size, void* d_ws, size_t ws_size,
                              hipStream_t stream) {
    const float* ys = (const float*)d_in[0];
    const int* labels = (const int*)d_in[1];
    float* out = (float*)d_out;

    unsigned char* yn = (unsigned char*)d_ws;                        // 8 MB fp8
    float* partials = (float*)((char*)d_ws + (size_t)ROWS * KDIM);   // 4.2 KB

    normalize_rows<<<ROWS, 256, 0, stream>>>(ys, (unsigned int*)yn);
    gram_loss<<<NJOBS, 256, 0, stream>>>(yn, labels, partials);
    finalize<<<1, 256, 0, stream>>>(partials, out);
}

// Round 6
// 46.744 us; speedup vs baseline: 4.0211x; 1.1327x over previous
//
#include <hip/hip_runtime.h>

// ContrastiveLoss: ys [4096,2048] f32, labels [4096] i32 -> scalar f32
// loss = mean over strict lower triangle of: same ? relu(2-cos)^2 : cos^2
// cos = pairwise cosine similarity of rows of ys (norm clamped at 1e-6).
//
// Round-6: round-5 structure (fp8 staging, 128x64 tiles, single-buffer LDS,
// 2 barriers per K-step) with the inner loop switched to MX-scaled
// mfma_scale_f32_16x16x128_f8f6f4 (unit scales 0x7F = 2^0): one MFMA eats
// the whole BK=128 slice -> 8 scaled MFMA + 12 ds_read_b128 per wave-step
// (was 32 MFMA + 24 ds_read_b64). Matrix cycles halve at the MX rate.

#define ROWS 4096
#define KDIM 2048
// Tile decomposition: 128-row x 64-col tiles over the lower triangle.
// bi in [0,32), bj in [0,64); keep bj <= 2*bi+1  -> sum(2bi+2) = 1056 jobs.
#define NJOBS 1056
#define BK 128          // k-elements (= bytes) per K-step
#define FSCALE 32.0f    // fp8 pre-scale
#define FSCALE2_INV (1.0f / (FSCALE * FSCALE))
#define SCALE_ONE 0x7F7F7F7F  // E8M0 exponent 127 -> 2^0 in every byte

typedef float f32x4 __attribute__((ext_vector_type(4)));
typedef int i32x4 __attribute__((ext_vector_type(4)));
typedef int i32x8 __attribute__((ext_vector_type(8)));

__device__ __forceinline__ void async_copy16(const unsigned char* g, unsigned char* l) {
    __builtin_amdgcn_global_load_lds(
        (const __attribute__((address_space(1))) void*)g,
        (__attribute__((address_space(3))) void*)l,
        16, 0, 0);
}

// ---------------- Kernel 1: row normalize, f32 -> fp8 e4m3 (x32) ----------
__global__ __launch_bounds__(256) void normalize_rows(
    const float* __restrict__ ys, unsigned int* __restrict__ yn) {
    int row = blockIdx.x;
    const float4* src = (const float4*)(ys + (size_t)row * KDIM);
    float4 vals[2];
    float ss = 0.f;
#pragma unroll
    for (int i = 0; i < 2; ++i) {
        float4 v = src[threadIdx.x + i * 256];
        vals[i] = v;
        ss += v.x * v.x + v.y * v.y + v.z * v.z + v.w * v.w;
    }
#pragma unroll
    for (int off = 32; off > 0; off >>= 1) ss += __shfl_down(ss, off);
    __shared__ float red[4];
    int lane = threadIdx.x & 63, wv = threadIdx.x >> 6;
    if (lane == 0) red[wv] = ss;
    __syncthreads();
    float tot = red[0] + red[1] + red[2] + red[3];
    float inv = FSCALE / fmaxf(sqrtf(tot), 1e-6f);
    unsigned int* dst = yn + (size_t)row * (KDIM / 4);
#pragma unroll
    for (int i = 0; i < 2; ++i) {
        float4 v = vals[i];
        int p = __builtin_amdgcn_cvt_pk_fp8_f32(v.x * inv, v.y * inv, 0, false);
        p = __builtin_amdgcn_cvt_pk_fp8_f32(v.z * inv, v.w * inv, p, true);
        dst[threadIdx.x + i * 256] = (unsigned int)p;
    }
}

// ---------------- Kernel 2: 128x64 Gram tile + fused loss -----------------
// 1056 linear blocks -> (bi,bj) lower-triangle jobs. 4 waves in 2x2; each
// wave owns a 64x32 subtile. Single-buffer LDS, 2 barriers per K-step,
// fp8 elements, MX-scaled K=128 MFMA with unit scales.
__global__ __launch_bounds__(256) void gram_loss(
    const unsigned char* __restrict__ yn, const int* __restrict__ labels,
    float* __restrict__ partials) {
    // XCD-chunk swizzle (bijective: 1056 % 8 == 0, 132 jobs per XCD):
    int t = (blockIdx.x & 7) * (NJOBS / 8) + (blockIdx.x >> 3);
    // job t -> (bi, bj): jobs for bi occupy [bi*(bi+1), bi*(bi+1)+2bi+2)
    int bi = (int)((sqrtf((float)(4 * t + 1)) - 1.0f) * 0.5f);
    while (bi * (bi + 1) > t) --bi;
    while ((bi + 1) * (bi + 2) <= t) ++bi;
    int bj = t - bi * (bi + 1);

    __shared__ __attribute__((aligned(16))) unsigned char As[128 * BK];  // 16KB
    __shared__ __attribute__((aligned(16))) unsigned char Bs[64 * BK];   // 8KB
    __shared__ int labI[128];
    __shared__ int labJ[64];
    __shared__ float red[4];

    int tid = threadIdx.x, lane = tid & 63, wv = tid >> 6;
    int wr = wv >> 1, wc = wv & 1;
    int rowA = bi * 128, rowB = bj * 64;

    if (tid < 128) labI[tid] = labels[rowA + tid];
    else if (tid < 192) labJ[tid - 128] = labels[rowB + tid - 128];

    // staging: chunk = 8 rows x 128 fp8 (1KB). lane covers row lane>>3,
    // 16B granule (lane&7) pre-XORed with row so linear LDS writes land
    // swizzled: byte ^= ((row&7)<<4).
    int srow = lane >> 3;
    int sbyte = ((lane & 7) ^ srow) * 16;

    f32x4 zero = {0.f, 0.f, 0.f, 0.f};
    f32x4 acc[4][2];
#pragma unroll
    for (int m = 0; m < 4; ++m)
#pragma unroll
        for (int n = 0; n < 2; ++n) acc[m][n] = zero;

    int colB = lane & 15;  // spatial index within 16x16 fragment
    int kq = lane >> 4;    // k-quarter: lane holds k = 32*kq .. +31

    for (int k0 = 0; k0 < KDIM; k0 += BK) {
        __syncthreads();  // previous tile fully consumed (labels on 1st iter)
        // 24 chunks: 0..15 -> A (16KB), 16..23 -> B (8KB); 6 iters x 4 waves
#pragma unroll
        for (int it = 0; it < 6; ++it) {
            int chunk = it * 4 + wv;
            if (chunk < 16) {
                int rr = chunk * 8 + srow;
                async_copy16(yn + (size_t)(rowA + rr) * KDIM + k0 + sbyte,
                             As + chunk * 1024);
            } else {
                int c2 = chunk - 16;
                int rr = c2 * 8 + srow;
                async_copy16(yn + (size_t)(rowB + rr) * KDIM + k0 + sbyte,
                             Bs + c2 * 1024);
            }
        }
        __syncthreads();  // vmcnt(0) drained by syncthreads semantics

        // One scaled MFMA (K=128) per fragment pair per K-step.
        // Lane kq's 32 true-k bytes sit at granules 2kq, 2kq+1; staging's
        // inverse-XOR means addr0 and addr0^16 give ascending k order.
        i32x8 af8[4];
#pragma unroll
        for (int m = 0; m < 4; ++m) {
            int row = wr * 64 + m * 16 + colB;
            int byte0 = (row * BK + kq * 32) ^ ((row & 7) << 4);
            i32x4 lo = *(const i32x4*)(As + byte0);
            i32x4 hi = *(const i32x4*)(As + (byte0 ^ 16));
            af8[m] = (i32x8){lo.x, lo.y, lo.z, lo.w, hi.x, hi.y, hi.z, hi.w};
        }
        i32x8 bf8v[2];
#pragma unroll
        for (int n = 0; n < 2; ++n) {
            int row = wc * 32 + n * 16 + colB;
            int byte0 = (row * BK + kq * 32) ^ ((row & 7) << 4);
            i32x4 lo = *(const i32x4*)(Bs + byte0);
            i32x4 hi = *(const i32x4*)(Bs + (byte0 ^ 16));
            bf8v[n] = (i32x8){lo.x, lo.y, lo.z, lo.w, hi.x, hi.y, hi.z, hi.w};
        }
#pragma unroll
        for (int m = 0; m < 4; ++m)
#pragma unroll
            for (int n = 0; n < 2; ++n)
                acc[m][n] = __builtin_amdgcn_mfma_scale_f32_16x16x128_f8f6f4(
                    af8[m], bf8v[n], acc[m][n],
                    0, 0,                  // cbsz=fp8, blgp=fp8
                    0, SCALE_ONE,          // opsel_a, scale_a (1.0)
                    0, SCALE_ONE);         // opsel_b, scale_b (1.0)
    }

    // fused loss epilogue: ti = wr*64+m*16+kq*4+j, tj = wc*32+n*16+colB
    float lsum = 0.f;
#pragma unroll
    for (int m = 0; m < 4; ++m) {
#pragma unroll
        for (int n = 0; n < 2; ++n) {
#pragma unroll
            for (int j = 0; j < 4; ++j) {
                int ti = wr * 64 + m * 16 + kq * 4 + j;
                int tj = wc * 32 + n * 16 + colB;
                int gi = rowA + ti, gj = rowB + tj;
                if (gi > gj) {
                    float c = acc[m][n][j] * FSCALE2_INV;
                    float v = (labI[ti] == labJ[tj]) ? fmaxf(2.0f - c, 0.0f) : c;
                    lsum += v * v;
                }
            }
        }
    }
#pragma unroll
    for (int off = 32; off > 0; off >>= 1) lsum += __shfl_down(lsum, off);
    if (lane == 0) red[wv] = lsum;
    __syncthreads();
    if (tid == 0) partials[blockIdx.x] = red[0] + red[1] + red[2] + red[3];
}

// ---------------- Kernel 3: deterministic final reduction -----------------
__global__ __launch_bounds__(256) void finalize(
    const float* __restrict__ partials, float* __restrict__ out) {
    float s = 0.f;
    for (int i = threadIdx.x; i < NJOBS; i += 256) s += partials[i];
#pragma unroll
    for (int off = 32; off > 0; off >>= 1) s += __shfl_down(s, off);
    __shared__ float red[4];
    int lane = threadIdx.x & 63, wv = threadIdx.x >> 6;
    if (lane == 0) red[wv] = s;
    __syncthreads();
    if (threadIdx.x == 0) {
        const double npair = (double)ROWS * (ROWS - 1) / 2.0;
        out[0] = (float)((double)(red[0] + red[1] + red[2] + red[3]) / npair);
    }
}

extern "C" void kernel_launch(void* const* d_in, const int* in_sizes, int n_in,
                              void* d_out, int out_size, void* d_ws, size_t ws_size,
                              hipStream_t stream) {
    const float* ys = (const float*)d_in[0];
    const int* labels = (const int*)d_in[1];
    float* out = (float*)d_out;

    unsigned char* yn = (unsigned char*)d_ws;                        // 8 MB fp8
    float* partials = (float*)((char*)d_ws + (size_t)ROWS * KDIM);   // 4.2 KB

    normalize_rows<<<ROWS, 256, 0, stream>>>(ys, (unsigned int*)yn);
    gram_loss<<<NJOBS, 256, 0, stream>>>(yn, labels, partials);
    finalize<<<1, 256, 0, stream>>>(partials, out);
}